// Round 13
// baseline (46.022 us; speedup 1.0000x reference)
//
#include <hip/hip_runtime.h>
#include <hip/hip_bf16.h>
#include <math.h>

#define C_DIM 384
#define NHEADS 6
#define HD 64
#define BATCH 8
#define NSEQ 1024
#define M_ROWS (BATCH * NSEQ)
#define LDP 40   // padded LDS row (bf16): 80B stride

typedef __attribute__((ext_vector_type(4))) float f32x4;
typedef __attribute__((ext_vector_type(8))) short s16x8;

__device__ __forceinline__ float bf2f(short u) {
  return __uint_as_float(((unsigned)(unsigned short)u) << 16);
}
__device__ __forceinline__ short f2bf(float f) {
  __hip_bfloat16 h = __float2bfloat16(f);
  return *reinterpret_cast<short*>(&h);
}
__device__ __forceinline__ s16x8 cvt8(float4 a, float4 b) {
  s16x8 r;
  r[0] = f2bf(a.x); r[1] = f2bf(a.y); r[2] = f2bf(a.z); r[3] = f2bf(a.w);
  r[4] = f2bf(b.x); r[5] = f2bf(b.y); r[6] = f2bf(b.z); r[7] = f2bf(b.w);
  return r;
}

__device__ __forceinline__ void gload_lds16(const void* g, void* l) {
  __builtin_amdgcn_global_load_lds(
      (const __attribute__((address_space(1))) unsigned int*)g,
      (__attribute__((address_space(3))) unsigned int*)l, 16, 0, 0);
}

__device__ __forceinline__ void wait_vm0() {
  asm volatile("s_waitcnt vmcnt(0)" ::: "memory");
}
__device__ __forceinline__ void lgkm0() {
  asm volatile("s_waitcnt lgkmcnt(0)" ::: "memory");
}
__device__ __forceinline__ void bar() {
  __builtin_amdgcn_sched_barrier(0);
  __builtin_amdgcn_s_barrier();
  __builtin_amdgcn_sched_barrier(0);
}

// ---------------------------------------------------------------------------
// Fused qkv-GEMM + local attention. One block per (128-row panel, head).
// 512 threads = 8 waves (2M x 4N; wave tile 64x48). GEMM: out[128][192] =
// x[rows][384] @ Wh[192][384]^T with Wh = head-h rows of q/k/v weight strips.
// Halo rows (rb-1, rb+128) of k,v computed by VALU dots (256 threads x 1 out).
// C-frags written directly into XOR-swizzled attn LDS; attention phase
// (attn_v3 phase-2) runs in-block; only the 128x64 attn output hits global.
// LDS (52KB): GEMM dbuf areas aliased by the attn q/k/v area after the loop.
// ---------------------------------------------------------------------------
__global__ __launch_bounds__(512) void qkv_attn(
    const float* __restrict__ x, const float* __restrict__ W,
    __hip_bfloat16* __restrict__ attn_out) {
  __shared__ __align__(16) ushort lds[25856];
  // ushort-index areas:
  //  As[buf]: buf*5120 + row*LDP + c              (row<128)
  //  Bs[buf]: 10240 + buf*7680 + row*LDP + c      (row<192)
  //  Ah fp32: ((float*)lds)+12800: [buf*64 + hrow*32 + k]   (bytes 51200..51711)
  //  attn alias (after K-loop): QOFF=0 KOFF=8192 VOFF=16512 (ends 24832)
  const int BSO = 10240;
  const int QOFF = 0, KOFF = 8192, VOFF = 16512;
  float* fh = (float*)lds + 12800;

  const int tid = threadIdx.x;
  // block mapping: 6 sibling head-blocks of a panel land on one XCD (id%8 const)
  const int g = blockIdx.x;                 // 0..383
  const int h = (g >> 3) % 6;
  const int panel = (g / 48) * 8 + (g & 7); // 0..63
  const int rb = panel << 7;
  const int b = rb >> 10;
  const int n0 = rb & 1023;

  const int lane = tid & 63;
  const int wave = tid >> 6;            // 0..7
  const int wr = (wave >> 2) * 64;      // 0,64
  const int wc = (wave & 3) * 48;       // 0,48,96,144
  const int l16 = lane & 15;
  const int lk8 = (lane >> 4) * 8;
  const int lr4 = (lane >> 4) * 4;

  // A staging: row sr (0..127), 8 fp32 at sc
  const int sr = tid >> 2;
  const int sc = (tid & 3) * 8;
  const float* aSrc = x + (size_t)(rb + sr) * C_DIM + sc;
  // B staging (tid<384): Wh row rB (0..191), 16 fp32 at cB
  const int rB = tid >> 1;
  const int cB = (tid & 1) * 16;
  const int strip = rB >> 6;            // 0=q,1=k,2=v
  const float* bSrc = W + (size_t)(strip * C_DIM + h * HD + (rB & 63)) * C_DIM + cB;
  // halo staging (tid<16): hrow (0,1), 4 fp32 at hc
  const int hsr = tid >> 3;             // 0,1
  const int hsc = (tid & 7) * 4;
  const int hg0 = b * NSEQ + (n0 > 0 ? n0 - 1 : 0);
  const int hg1 = b * NSEQ + (n0 + 128 < NSEQ ? n0 + 128 : NSEQ - 1);
  const float* hSrc = x + (size_t)(hsr ? hg1 : hg0) * C_DIM + hsc;
  // halo compute (tid<256): one (hrow, col) output
  const int hrow = tid >> 7;            // 0,1
  const int hcol = tid & 127;           // 0..127 -> Bs row 64+hcol

  f32x4 acc[4][3] = {};
  float hacc = 0.f;
  float4 aL[2], bL[4], hL;

  auto loadRegs = [&](int kt) {
    const float4* ap = (const float4*)(aSrc + kt * 32);
    aL[0] = ap[0]; aL[1] = ap[1];
    if (tid < 384) {
      const float4* bp = (const float4*)(bSrc + kt * 32);
      bL[0] = bp[0]; bL[1] = bp[1]; bL[2] = bp[2]; bL[3] = bp[3];
    }
    if (tid < 16) hL = *(const float4*)(hSrc + kt * 32);
  };
  auto writeLds = [&](int buf) {
    *(s16x8*)(lds + buf * 5120 + sr * LDP + sc) = cvt8(aL[0], aL[1]);
    if (tid < 384) {
      *(s16x8*)(lds + BSO + buf * 7680 + rB * LDP + cB)     = cvt8(bL[0], bL[1]);
      *(s16x8*)(lds + BSO + buf * 7680 + rB * LDP + cB + 8) = cvt8(bL[2], bL[3]);
    }
    if (tid < 16) *(float4*)(fh + buf * 64 + hsr * 32 + hsc) = hL;
  };

  loadRegs(0);
  const int nkt = C_DIM >> 5;  // 12
  for (int kt = 0; kt < nkt; ++kt) {
    const int cur = kt & 1;
    wait_vm0();
    __builtin_amdgcn_sched_barrier(0);
    writeLds(cur);
    if (kt + 1 < nkt) loadRegs(kt + 1);
    lgkm0();
    bar();

    s16x8 af[4], bfr[3];
#pragma unroll
    for (int m = 0; m < 4; ++m)
      af[m] = *(const s16x8*)(lds + cur * 5120 + (wr + m * 16 + l16) * LDP + lk8);
#pragma unroll
    for (int n = 0; n < 3; ++n)
      bfr[n] = *(const s16x8*)(lds + BSO + cur * 7680 + (wc + n * 16 + l16) * LDP + lk8);
#pragma unroll
    for (int m = 0; m < 4; ++m)
#pragma unroll
      for (int n = 0; n < 3; ++n)
        acc[m][n] = __builtin_amdgcn_mfma_f32_16x16x32_bf16(
            af[m], bfr[n], acc[m][n], 0, 0, 0);

    if (tid < 256) {  // halo k,v rows: 32 MACs on the VALU pipe
      const ushort* brow = lds + BSO + cur * 7680 + (64 + hcol) * LDP;
      const float* ah = fh + cur * 64 + hrow * 32;
#pragma unroll
      for (int kk = 0; kk < 4; ++kk) {
        s16x8 bv = *(const s16x8*)(brow + kk * 8);
#pragma unroll
        for (int e = 0; e < 8; ++e)
          hacc += ah[kk * 8 + e] * bf2f(bv[e]);
      }
    }
    bar();
  }

  // ---- C-frags -> swizzled attn LDS (aliases As/Bs; all reads done) ----
#pragma unroll
  for (int m = 0; m < 4; ++m) {
#pragma unroll
    for (int n = 0; n < 3; ++n) {
      int col = wc + n * 16 + l16;      // 0..191
#pragma unroll
      for (int j = 0; j < 4; ++j) {
        int row = wr + m * 16 + lr4 + j;
        short hv = f2bf(acc[m][n][j]);
        int base, d, arow;
        if (col < 64)       { base = QOFF; d = col;       arow = row; }
        else if (col < 128) { base = KOFF; d = col - 64;  arow = row + 1; }
        else                { base = VOFF; d = col - 128; arow = row + 1; }
        lds[base + (arow * 8 + ((d >> 3) ^ (arow & 7))) * 8 + (d & 7)] = (ushort)hv;
      }
    }
  }
  if (tid < 256) {
    int arow = hrow ? 129 : 0;
    int base = (hcol < 64) ? KOFF : VOFF;
    int d = (hcol < 64) ? hcol : hcol - 64;
    lds[base + (arow * 8 + ((d >> 3) ^ (arow & 7))) * 8 + (d & 7)] = (ushort)f2bf(hacc);
  }
  __syncthreads();

  // ---- attention phase (attn_v3 phase-2, tid<256) ----
  if (tid < 256) {
    const int r = tid >> 1;
    const int half = tid & 1;
    const int jbase = half * 4;
    const int n = n0 + r;

    float qf[32];
#pragma unroll
    for (int c = 0; c < 4; ++c) {
      int slot = r * 8 + ((jbase + c) ^ (r & 7));
      s16x8 v = *(const s16x8*)(lds + QOFF + slot * 8);
#pragma unroll
      for (int e = 0; e < 8; ++e) qf[c * 8 + e] = bf2f(v[e]);
    }

    float s3[3];
#pragma unroll
    for (int jj = 0; jj < 3; ++jj) {
      int krow = r + jj;
      float a = 0.f;
#pragma unroll
      for (int c = 0; c < 4; ++c) {
        int slot = krow * 8 + ((jbase + c) ^ (krow & 7));
        s16x8 v = *(const s16x8*)(lds + KOFF + slot * 8);
#pragma unroll
        for (int e = 0; e < 8; ++e) a += qf[c * 8 + e] * bf2f(v[e]);
      }
      a += __shfl_xor(a, 1);
      s3[jj] = ((unsigned)(n + jj - 1) < (unsigned)NSEQ) ? a * 0.125f : -1e30f;
    }

    float mx = fmaxf(s3[0], fmaxf(s3[1], s3[2]));
    float p0 = __expf(s3[0] - mx);
    float p1 = __expf(s3[1] - mx);
    float p2 = __expf(s3[2] - mx);
    float inv = 1.f / (p0 + p1 + p2);
    float p[3] = {p0 * inv, p1 * inv, p2 * inv};

    float of[32] = {};
#pragma unroll
    for (int jj = 0; jj < 3; ++jj) {
      int krow = r + jj;
      float pw = p[jj];
#pragma unroll
      for (int c = 0; c < 4; ++c) {
        int slot = krow * 8 + ((jbase + c) ^ (krow & 7));
        s16x8 v = *(const s16x8*)(lds + VOFF + slot * 8);
#pragma unroll
        for (int e = 0; e < 8; ++e) of[c * 8 + e] += pw * bf2f(v[e]);
      }
    }

#pragma unroll
    for (int c = 0; c < 4; ++c) {
      s16x8 o;
#pragma unroll
      for (int e = 0; e < 8; ++e) o[e] = f2bf(of[c * 8 + e]);
      *(s16x8*)(attn_out + (size_t)(rb + r) * C_DIM + h * HD + jbase * 8 + c * 8) = o;
    }
  }
}

// ---------------------------------------------------------------------------
// gemm2 (R6 champion version, verbatim): out = attn @ proj_w^T + b.
// A=attn bf16 (global_load_lds staged), W=proj_w fp32 (reg-staged + cvt).
// BM=128, BN=64, 256 threads.
// ---------------------------------------------------------------------------
__global__ __launch_bounds__(256) void gemm2_mix(
    const __hip_bfloat16* __restrict__ A, const float* __restrict__ W,
    const float* __restrict__ bias, float* __restrict__ outp,
    int M, int N, int K) {
  __shared__ __align__(16) __hip_bfloat16 As[2][128 * 32];
  __shared__ __align__(16) __hip_bfloat16 Bs[2][64 * 32];

  const int tid = threadIdx.x;
  const int nwg = gridDim.x * gridDim.y;           // 384, %8==0
  const int bid0 = blockIdx.y * gridDim.x + blockIdx.x;
  const int cpx = nwg >> 3;
  const int wg = (bid0 & 7) * cpx + (bid0 >> 3);
  const int bx = wg % gridDim.x;
  const int by = wg / gridDim.x;

  const int lane = tid & 63;
  const int wave = tid >> 6;
  const int wr = (wave >> 1) * 64;
  const int wc = (wave & 1) * 32;
  const int rowBase = by * 128;
  const int colBase = bx * 64;
  const int l16 = lane & 15;
  const int lk8 = (lane >> 4) * 8;
  const int lr4 = (lane >> 4) * 4;

  const int sr = tid >> 2;
  const int sc = (tid & 3) * 8;
  const float* bSrc = W + (size_t)(colBase + sr) * K + sc;

  f32x4 acc[4][2] = {};
  float4 bL[2];

  auto stageA = [&](int kt, int buf) {
#pragma unroll
    for (int i = 0; i < 2; ++i) {
      int c = tid + i * 256;
      int r = c >> 2, cc = (c & 3) * 8;
      gload_lds16(A + (size_t)(rowBase + r) * K + kt * 32 + cc, &As[buf][c * 8]);
    }
  };
  auto loadB = [&](int kt) {
    const float4* bp = (const float4*)(bSrc + kt * 32);
    bL[0] = bp[0]; bL[1] = bp[1];
  };

  stageA(0, 0);
  loadB(0);
  const int nkt = K >> 5;
  for (int kt = 0; kt < nkt; ++kt) {
    const int cur = kt & 1;
    wait_vm0();
    __builtin_amdgcn_sched_barrier(0);
    *(s16x8*)&Bs[cur][sr * 32 + sc] = cvt8(bL[0], bL[1]);
    if (kt + 1 < nkt) {
      stageA(kt + 1, cur ^ 1);
      loadB(kt + 1);
    }
    lgkm0();
    bar();

    s16x8 af[4], bfr[2];
#pragma unroll
    for (int m = 0; m < 4; ++m)
      af[m] = *(const s16x8*)(&As[cur][(wr + m * 16 + l16) * 32 + lk8]);
#pragma unroll
    for (int n = 0; n < 2; ++n)
      bfr[n] = *(const s16x8*)(&Bs[cur][(wc + n * 16 + l16) * 32 + lk8]);
#pragma unroll
    for (int m = 0; m < 4; ++m)
#pragma unroll
      for (int n = 0; n < 2; ++n)
        acc[m][n] = __builtin_amdgcn_mfma_f32_16x16x32_bf16(
            af[m], bfr[n], acc[m][n], 0, 0, 0);
    bar();
  }

#pragma unroll
  for (int m = 0; m < 4; ++m) {
    int rb = rowBase + wr + m * 16 + lr4;
#pragma unroll
    for (int n = 0; n < 2; ++n) {
      int cb = colBase + wc + n * 16 + l16;
      float bv = bias[cb];
#pragma unroll
      for (int j = 0; j < 4; ++j)
        outp[(size_t)(rb + j) * N + cb] = acc[m][n][j] + bv;
    }
  }
}

extern "C" void kernel_launch(void* const* d_in, const int* in_sizes, int n_in,
                              void* d_out, int out_size, void* d_ws, size_t ws_size,
                              hipStream_t stream) {
  const float* x      = (const float*)d_in[0];  // [B,N,C]
  const float* qkv_w  = (const float*)d_in[1];  // [3C,C]
  const float* proj_w = (const float*)d_in[2];  // [C,C]
  const float* proj_b = (const float*)d_in[3];  // [C]
  float* out = (float*)d_out;                   // [B,N,C] fp32

  __hip_bfloat16* attn_bf = (__hip_bfloat16*)d_ws;   // [8192,384]

  // 1) fused qkv-GEMM + local attention: 64 panels x 6 heads = 384 blocks
  qkv_attn<<<384, 512, 0, stream>>>(x, qkv_w, attn_bf);

  // 2) out = attn @ proj_w^T + proj_b, 6x64 = 384 blocks
  gemm2_mix<<<dim3(6, 64), 256, 0, stream>>>(
      attn_bf, proj_w, proj_b, out, M_ROWS, C_DIM, C_DIM);
}

// Round 14
// 42.955 us; speedup vs baseline: 1.0714x; 1.0714x over previous
//
#include <hip/hip_runtime.h>
#include <hip/hip_bf16.h>
#include <math.h>

#define C_DIM 384
#define NHEADS 6
#define HD 64
#define BATCH 8
#define NSEQ 1024
#define M_ROWS (BATCH * NSEQ)

typedef __attribute__((ext_vector_type(4))) float f32x4;
typedef __attribute__((ext_vector_type(8))) short s16x8;

__device__ __forceinline__ float bf2f(short u) {
  return __uint_as_float(((unsigned)(unsigned short)u) << 16);
}
__device__ __forceinline__ short f2bf(float f) {
  __hip_bfloat16 h = __float2bfloat16(f);
  return *reinterpret_cast<short*>(&h);
}
__device__ __forceinline__ s16x8 cvt8(float4 a, float4 b) {
  s16x8 r;
  r[0] = f2bf(a.x); r[1] = f2bf(a.y); r[2] = f2bf(a.z); r[3] = f2bf(a.w);
  r[4] = f2bf(b.x); r[5] = f2bf(b.y); r[6] = f2bf(b.z); r[7] = f2bf(b.w);
  return r;
}

__device__ __forceinline__ void gload_lds16(const void* g, void* l) {
  __builtin_amdgcn_global_load_lds(
      (const __attribute__((address_space(1))) unsigned int*)g,
      (__attribute__((address_space(3))) unsigned int*)l, 16, 0, 0);
}

__device__ __forceinline__ void wait_vm0() {
  asm volatile("s_waitcnt vmcnt(0)" ::: "memory");
}
__device__ __forceinline__ void lgkm0() {
  asm volatile("s_waitcnt lgkmcnt(0)" ::: "memory");
}
__device__ __forceinline__ void bar() {
  __builtin_amdgcn_sched_barrier(0);
  __builtin_amdgcn_s_barrier();
  __builtin_amdgcn_sched_barrier(0);
}

// ---------------------------------------------------------------------------
// gemm1: qkv = x @ qkv_w^T. A=x fp32 [M,K], W=qkv_w fp32 [N,K], out bf16.
// BM=128, BN=128, BK=32, 512 threads = 8 waves (2x4; wave tile 64x32).
// Both operands reg-staged fp32 -> cvt bf16 -> ds_write (fused cast).
// Double-buffered LDS; next-tile loads issued before the barrier and kept
// in flight across it (raw s_barrier, counted wait at loop top only).
// ---------------------------------------------------------------------------
__global__ __launch_bounds__(512) void gemm1_rs(
    const float* __restrict__ A, const float* __restrict__ W,
    __hip_bfloat16* __restrict__ outp, int M, int N, int K) {
  __shared__ __align__(16) __hip_bfloat16 As[2][128 * 32];
  __shared__ __align__(16) __hip_bfloat16 Bs[2][128 * 32];

  const int tid = threadIdx.x;
  const int nwg = gridDim.x * gridDim.y;           // 576, %8==0
  const int bid0 = blockIdx.y * gridDim.x + blockIdx.x;
  const int cpx = nwg >> 3;
  const int wg = (bid0 & 7) * cpx + (bid0 >> 3);   // bijective XCD swizzle
  const int bx = wg % gridDim.x;
  const int by = wg / gridDim.x;

  const int lane = tid & 63;
  const int wave = tid >> 6;          // 0..7
  const int wr = (wave >> 2) * 64;    // 0,64
  const int wc = (wave & 3) * 32;     // 0,32,64,96
  const int rowBase = by * 128;
  const int colBase = bx * 128;
  const int l16 = lane & 15;
  const int lk8 = (lane >> 4) * 8;
  const int lr4 = (lane >> 4) * 4;

  // staging: thread covers row sr (0..127), 8 consecutive cols at sc
  const int sr = tid >> 2;
  const int sc = (tid & 3) * 8;
  const float* aSrc = A + (size_t)(rowBase + sr) * K + sc;
  const float* bSrc = W + (size_t)(colBase + sr) * K + sc;

  f32x4 acc[4][2] = {};
  float4 aL[2], bL[2];

  auto loadRegs = [&](int kt) {
    const float4* ap = (const float4*)(aSrc + kt * 32);
    aL[0] = ap[0]; aL[1] = ap[1];
    const float4* bp = (const float4*)(bSrc + kt * 32);
    bL[0] = bp[0]; bL[1] = bp[1];
  };

  loadRegs(0);
  const int nkt = K >> 5;  // 12
  for (int kt = 0; kt < nkt; ++kt) {
    const int cur = kt & 1;
    wait_vm0();
    __builtin_amdgcn_sched_barrier(0);
    *(s16x8*)&As[cur][sr * 32 + sc] = cvt8(aL[0], aL[1]);
    *(s16x8*)&Bs[cur][sr * 32 + sc] = cvt8(bL[0], bL[1]);
    if (kt + 1 < nkt) loadRegs(kt + 1);  // in flight across barrier + MFMA
    lgkm0();
    bar();

    s16x8 af[4], bfr[2];
#pragma unroll
    for (int m = 0; m < 4; ++m)
      af[m] = *(const s16x8*)(&As[cur][(wr + m * 16 + l16) * 32 + lk8]);
#pragma unroll
    for (int n = 0; n < 2; ++n)
      bfr[n] = *(const s16x8*)(&Bs[cur][(wc + n * 16 + l16) * 32 + lk8]);
#pragma unroll
    for (int m = 0; m < 4; ++m)
#pragma unroll
      for (int n = 0; n < 2; ++n)
        acc[m][n] = __builtin_amdgcn_mfma_f32_16x16x32_bf16(
            af[m], bfr[n], acc[m][n], 0, 0, 0);
    bar();
  }

#pragma unroll
  for (int m = 0; m < 4; ++m) {
    int rb = rowBase + wr + m * 16 + lr4;
#pragma unroll
    for (int n = 0; n < 2; ++n) {
      int cb = colBase + wc + n * 16 + l16;
#pragma unroll
      for (int j = 0; j < 4; ++j)
        outp[(size_t)(rb + j) * N + cb] = __float2bfloat16(acc[m][n][j]);
    }
  }
}

// ---------------------------------------------------------------------------
// gemm2: out = attn @ proj_w^T + b. A=attn bf16 (global_load_lds staged),
// W=proj_w fp32 (reg-staged + cvt), out fp32. BM=128, BN=64, 256 threads.
// ---------------------------------------------------------------------------
__global__ __launch_bounds__(256) void gemm2_mix(
    const __hip_bfloat16* __restrict__ A, const float* __restrict__ W,
    const float* __restrict__ bias, float* __restrict__ outp,
    int M, int N, int K) {
  __shared__ __align__(16) __hip_bfloat16 As[2][128 * 32];
  __shared__ __align__(16) __hip_bfloat16 Bs[2][64 * 32];

  const int tid = threadIdx.x;
  const int nwg = gridDim.x * gridDim.y;           // 384, %8==0
  const int bid0 = blockIdx.y * gridDim.x + blockIdx.x;
  const int cpx = nwg >> 3;
  const int wg = (bid0 & 7) * cpx + (bid0 >> 3);
  const int bx = wg % gridDim.x;
  const int by = wg / gridDim.x;

  const int lane = tid & 63;
  const int wave = tid >> 6;        // 0..3
  const int wr = (wave >> 1) * 64;  // 0,64
  const int wc = (wave & 1) * 32;   // 0,32
  const int rowBase = by * 128;
  const int colBase = bx * 64;
  const int l16 = lane & 15;
  const int lk8 = (lane >> 4) * 8;
  const int lr4 = (lane >> 4) * 4;

  const int sr = tid >> 2;          // 0..63 (B rows)
  const int sc = (tid & 3) * 8;
  const float* bSrc = W + (size_t)(colBase + sr) * K + sc;

  f32x4 acc[4][2] = {};
  float4 bL[2];

  auto stageA = [&](int kt, int buf) {
#pragma unroll
    for (int i = 0; i < 2; ++i) {
      int c = tid + i * 256;
      int r = c >> 2, cc = (c & 3) * 8;
      gload_lds16(A + (size_t)(rowBase + r) * K + kt * 32 + cc, &As[buf][c * 8]);
    }
  };
  auto loadB = [&](int kt) {
    const float4* bp = (const float4*)(bSrc + kt * 32);
    bL[0] = bp[0]; bL[1] = bp[1];
  };

  stageA(0, 0);
  loadB(0);
  const int nkt = K >> 5;  // 12
  for (int kt = 0; kt < nkt; ++kt) {
    const int cur = kt & 1;
    wait_vm0();                       // A(kt) in LDS, B(kt) in regs
    __builtin_amdgcn_sched_barrier(0);
    *(s16x8*)&Bs[cur][sr * 32 + sc] = cvt8(bL[0], bL[1]);
    if (kt + 1 < nkt) {
      stageA(kt + 1, cur ^ 1);        // safe: all waves done reading cur^1
      loadB(kt + 1);
    }
    lgkm0();
    bar();

    s16x8 af[4], bfr[2];
#pragma unroll
    for (int m = 0; m < 4; ++m)
      af[m] = *(const s16x8*)(&As[cur][(wr + m * 16 + l16) * 32 + lk8]);
#pragma unroll
    for (int n = 0; n < 2; ++n)
      bfr[n] = *(const s16x8*)(&Bs[cur][(wc + n * 16 + l16) * 32 + lk8]);
#pragma unroll
    for (int m = 0; m < 4; ++m)
#pragma unroll
      for (int n = 0; n < 2; ++n)
        acc[m][n] = __builtin_amdgcn_mfma_f32_16x16x32_bf16(
            af[m], bfr[n], acc[m][n], 0, 0, 0);
    bar();
  }

#pragma unroll
  for (int m = 0; m < 4; ++m) {
    int rb = rowBase + wr + m * 16 + lr4;
#pragma unroll
    for (int n = 0; n < 2; ++n) {
      int cb = colBase + wc + n * 16 + l16;
      float bv = bias[cb];
#pragma unroll
      for (int j = 0; j < 4; ++j)
        outp[(size_t)(rb + j) * N + cb] = acc[m][n][j] + bv;
    }
  }
}

// ---------------------------------------------------------------------------
// Local attention: one block per (128-row panel, head). LDS-staged q/k/v with
// XOR-pre-swizzled global source (linear LDS dest), 2 threads per row.
// ---------------------------------------------------------------------------
__global__ __launch_bounds__(256) void local_attn_v3(
    const __hip_bfloat16* __restrict__ qkv, __hip_bfloat16* __restrict__ attn_out) {
  __shared__ __align__(16) ushort lds[24832];
  const int QOFF = 0;
  const int KOFF = 8192;
  const int VOFF = 8192 + 8320;

  const int tid = threadIdx.x;
  const int mb = blockIdx.x & 63;
  const int h  = blockIdx.x >> 6;
  const int rb = mb * 128;
  const int b  = rb >> 10;
  const int n0 = rb & 1023;
  const int RS = 3 * C_DIM;

#pragma unroll
  for (int i = 0; i < 4; ++i) {
    int s = i * 256 + tid;
    int r = s >> 3;
    int jg = (s & 7) ^ (r & 7);
    gload_lds16(qkv + (size_t)(rb + r) * RS + h * HD + jg * 8,
                lds + QOFF + s * 8);
  }
#pragma unroll
  for (int i = 0; i < 5; ++i) {
    int s = i * 256 + tid;
    if (s < 1040) {
      int r = s >> 3;
      int jg = (s & 7) ^ (r & 7);
      int nl = n0 + r - 1;
      nl = nl < 0 ? 0 : (nl > 1023 ? 1023 : nl);
      size_t row = (size_t)(b << 10) + nl;
      gload_lds16(qkv + row * RS + C_DIM + h * HD + jg * 8, lds + KOFF + s * 8);
      gload_lds16(qkv + row * RS + 2 * C_DIM + h * HD + jg * 8, lds + VOFF + s * 8);
    }
  }
  __syncthreads();

  const int r = tid >> 1;
  const int half = tid & 1;
  const int jbase = half * 4;
  const int n = n0 + r;

  float qf[32];
#pragma unroll
  for (int c = 0; c < 4; ++c) {
    int slot = r * 8 + ((jbase + c) ^ (r & 7));
    s16x8 v = *(const s16x8*)(lds + QOFF + slot * 8);
#pragma unroll
    for (int e = 0; e < 8; ++e) qf[c * 8 + e] = bf2f(v[e]);
  }

  float s3[3];
#pragma unroll
  for (int jj = 0; jj < 3; ++jj) {
    int krow = r + jj;
    float acc = 0.f;
#pragma unroll
    for (int c = 0; c < 4; ++c) {
      int slot = krow * 8 + ((jbase + c) ^ (krow & 7));
      s16x8 v = *(const s16x8*)(lds + KOFF + slot * 8);
#pragma unroll
      for (int e = 0; e < 8; ++e) acc += qf[c * 8 + e] * bf2f(v[e]);
    }
    acc += __shfl_xor(acc, 1);
    s3[jj] = ((unsigned)(n + jj - 1) < (unsigned)NSEQ) ? acc * 0.125f : -1e30f;
  }

  float mx = fmaxf(s3[0], fmaxf(s3[1], s3[2]));
  float p0 = __expf(s3[0] - mx);
  float p1 = __expf(s3[1] - mx);
  float p2 = __expf(s3[2] - mx);
  float inv = 1.f / (p0 + p1 + p2);
  float p[3] = {p0 * inv, p1 * inv, p2 * inv};

  float of[32] = {};
#pragma unroll
  for (int jj = 0; jj < 3; ++jj) {
    int krow = r + jj;
    float pw = p[jj];
#pragma unroll
    for (int c = 0; c < 4; ++c) {
      int slot = krow * 8 + ((jbase + c) ^ (krow & 7));
      s16x8 v = *(const s16x8*)(lds + VOFF + slot * 8);
#pragma unroll
      for (int e = 0; e < 8; ++e) of[c * 8 + e] += pw * bf2f(v[e]);
    }
  }

#pragma unroll
  for (int c = 0; c < 4; ++c) {
    s16x8 o;
#pragma unroll
    for (int e = 0; e < 8; ++e) o[e] = f2bf(of[c * 8 + e]);
    *(s16x8*)(attn_out + (size_t)(rb + r) * C_DIM + h * HD + jbase * 8 + c * 8) = o;
  }
}

extern "C" void kernel_launch(void* const* d_in, const int* in_sizes, int n_in,
                              void* d_out, int out_size, void* d_ws, size_t ws_size,
                              hipStream_t stream) {
  const float* x      = (const float*)d_in[0];  // [B,N,C]
  const float* qkv_w  = (const float*)d_in[1];  // [3C,C]
  const float* proj_w = (const float*)d_in[2];  // [C,C]
  const float* proj_b = (const float*)d_in[3];  // [C]
  float* out = (float*)d_out;                   // [B,N,C] fp32

  __hip_bfloat16* qkv_bf  = (__hip_bfloat16*)d_ws;                 // [8192,1152]
  __hip_bfloat16* attn_bf = qkv_bf + (size_t)M_ROWS * 3 * C_DIM;   // [8192,384]

  // 1) qkv = x @ qkv_w^T (fused fp32->bf16 cast in staging), 9x64 = 576 blocks
  gemm1_rs<<<dim3(9, 64), 512, 0, stream>>>(
      x, qkv_w, qkv_bf, M_ROWS, 3 * C_DIM, C_DIM);

  // 2) banded local attention (window 3): 64 row-panels x 6 heads
  local_attn_v3<<<64 * NHEADS, 256, 0, stream>>>(qkv_bf, attn_bf);

  // 3) out = attn @ proj_w^T + proj_b (fused W cast), 6x64 = 384 blocks
  gemm2_mix<<<dim3(6, 64), 256, 0, stream>>>(
      attn_bf, proj_w, proj_b, out, M_ROWS, C_DIM, C_DIM);
}